// Round 24
// baseline (464.960 us; speedup 1.0000x reference)
//
#include <hip/hip_runtime.h>
#include <math.h>
#include <stdint.h>

#define B_N 32768
#define V_N 2048
#define H_N 256
#define E_N 16
#define Q_N 4

#define KT 64
#define NSTRIP (V_N/KT)   // 32
#define BROWS 32
#define KG_N (V_N/8)      // 256 k-groups
#define NSS (V_N/128)     // 16 superstrips

#define RNG_PART 1

typedef double f64x4 __attribute__((ext_vector_type(4)));
typedef float  f32x4 __attribute__((ext_vector_type(4)));
typedef short  bf16x8 __attribute__((ext_vector_type(8)));

union U8 { unsigned u[4]; bf16x8 v; };

// ---------------- Threefry2x32 (JAX-exact, 20 rounds; KAT-verified on HW r2) ----------------
#define TF_R(x0,x1,r) { x0 += x1; x1 = ((x1 << (r)) | (x1 >> (32-(r)))); x1 ^= x0; }

__device__ __forceinline__ void tf_block(uint32_t k0, uint32_t k1, uint32_t &x0, uint32_t &x1){
  uint32_t k2 = k0 ^ k1 ^ 0x1BD11BDAu;
  x0 += k0; x1 += k1;
  TF_R(x0,x1,13) TF_R(x0,x1,15) TF_R(x0,x1,26) TF_R(x0,x1,6)
  x0 += k1; x1 += k2 + 1u;
  TF_R(x0,x1,17) TF_R(x0,x1,29) TF_R(x0,x1,16) TF_R(x0,x1,24)
  x0 += k2; x1 += k0 + 2u;
  TF_R(x0,x1,13) TF_R(x0,x1,15) TF_R(x0,x1,26) TF_R(x0,x1,6)
  x0 += k0; x1 += k1 + 3u;
  TF_R(x0,x1,17) TF_R(x0,x1,29) TF_R(x0,x1,16) TF_R(x0,x1,24)
  x0 += k1; x1 += k2 + 4u;
  TF_R(x0,x1,13) TF_R(x0,x1,15) TF_R(x0,x1,26) TF_R(x0,x1,6)
  x0 += k2; x1 += k0 + 5u;
}

__device__ __forceinline__ int run_kats(){
  uint32_t x0, x1;
  x0 = 0u; x1 = 0u;
  tf_block(0u, 0u, x0, x1);
  if (x0 != 0x6b200159u || x1 != 0x99ba4efeu) return 1;
  x0 = 0xFFFFFFFFu; x1 = 0xFFFFFFFFu;
  tf_block(0xFFFFFFFFu, 0xFFFFFFFFu, x0, x1);
  if (x0 != 0x1cb996fcu || x1 != 0xbb002be7u) return 2;
  x0 = 0x243f6a88u; x1 = 0x85a308d3u;
  tf_block(0x13198a2eu, 0x03707344u, x0, x1);
  if (x0 != 0xc4923a9cu || x1 != 0x483df7a0u) return 3;
  return 0;
}

__device__ __forceinline__ uint32_t rbits(uint32_t ka, uint32_t kb, uint32_t b){
#if RNG_PART
  uint32_t x0 = 0u, x1 = b;
  tf_block(ka, kb, x0, x1);
  return x0 ^ x1;
#else
  uint32_t i = b & 16383u;
  uint32_t x0 = i, x1 = i + 16384u;
  tf_block(ka, kb, x0, x1);
  return (b < 16384u) ? x0 : x1;
#endif
}

// ---------------- fast f64 tanh (~3 ulp), HW-gated vs libm in s0 ----------------
__device__ __forceinline__ double exp_pos_f64(double v){
  const double LOG2E  = 1.4426950408889634074;
  const double LN2HI  = 6.93147180369123816490e-01;
  const double LN2LO  = 1.90821492927058770002e-10;
  double k = rint(v * LOG2E);
  double r = fma(-k, LN2HI, v);
  r = fma(-k, LN2LO, r);
  double p = 1.6059043836821613e-10;
  p = fma(p, r, 2.08767569878681e-09);
  p = fma(p, r, 2.505210838544172e-08);
  p = fma(p, r, 2.7557319223985893e-07);
  p = fma(p, r, 2.755731922398589e-06);
  p = fma(p, r, 2.48015873015873e-05);
  p = fma(p, r, 1.984126984126984e-04);
  p = fma(p, r, 1.3888888888888889e-03);
  p = fma(p, r, 8.333333333333333e-03);
  p = fma(p, r, 4.1666666666666664e-02);
  p = fma(p, r, 1.6666666666666666e-01);
  p = fma(p, r, 5.0e-01);
  p = fma(p, r, 1.0);
  p = fma(p, r, 1.0);
  int n = (int)k;
  double sc = __longlong_as_double(((long long)(1023 + n)) << 52);
  return p * sc;
}

__device__ __forceinline__ double tanh_fast(double x){
  double ax = fabs(x);
  if (ax < 0.25){
    double z = x * x;
    double p = 9.691537956929451e-05;
    p = fma(p, z, -2.3912911424355248e-04);
    p = fma(p, z,  5.900274409455859e-04);
    p = fma(p, z, -1.4558343870513183e-03);
    p = fma(p, z,  3.592128036572481e-03);
    p = fma(p, z, -8.863235529902197e-03);
    p = fma(p, z,  2.1869488536155203e-02);
    p = fma(p, z, -5.396825396825397e-02);
    p = fma(p, z,  1.3333333333333333e-01);
    p = fma(p, z, -3.3333333333333333e-01);
    double q = fma(p, z, 1.0);
    return x * q;
  }
  if (ax > 19.0) return copysign(1.0, x);
  double y = exp_pos_f64(2.0 * ax);
  double t = 1.0 - 2.0/(y + 1.0);
  return copysign(t, x);
}

__device__ __forceinline__ double tanh_d(double x, unsigned slow){
  return slow ? tanh(x) : tanh_fast(x);
}

// ---------------- exact 3-way bf16 split ----------------
__device__ __forceinline__ unsigned cvt_pk_bf16(float a, float b){
  unsigned r;
  asm("v_cvt_pk_bf16_f32 %0, %1, %2" : "=v"(r) : "v"(a), "v"(b));
  return r;
}

template<bool CV>
__device__ __forceinline__ void splitpair(float a, float b, unsigned &uh, unsigned &um, unsigned &ul){
  float ha, hb, ma, mb;
  if (CV){
    uh = cvt_pk_bf16(a, b);
    ha = __uint_as_float(uh<<16); hb = __uint_as_float(uh & 0xFFFF0000u);
  } else {
    unsigned ua=__float_as_uint(a), ub=__float_as_uint(b);
    uh = (ua>>16) | (ub & 0xFFFF0000u);
    ha = __uint_as_float(ua & 0xFFFF0000u); hb = __uint_as_float(ub & 0xFFFF0000u);
  }
  float ra = a - ha, rb = b - hb;
  if (CV){
    um = cvt_pk_bf16(ra, rb);
    ma = __uint_as_float(um<<16); mb = __uint_as_float(um & 0xFFFF0000u);
  } else {
    unsigned va=__float_as_uint(ra), vb=__float_as_uint(rb);
    um = (va>>16) | (vb & 0xFFFF0000u);
    ma = __uint_as_float(va & 0xFFFF0000u); mb = __uint_as_float(vb & 0xFFFF0000u);
  }
  float sa = ra - ma, sb = rb - mb;
  if (CV) ul = cvt_pk_bf16(sa, sb);
  else    ul = (__float_as_uint(sa)>>16) | (__float_as_uint(sb) & 0xFFFF0000u);
}

template<bool CV>
__device__ __forceinline__ void split8(const float* v, bf16x8& fh, bf16x8& fm, bf16x8& fl){
  U8 H, M, L;
  #pragma unroll
  for (int p=0;p<4;++p)
    splitpair<CV>(v[2*p], v[2*p+1], H.u[p], M.u[p], L.u[p]);
  fh=H.v; fm=M.v; fl=L.v;
}

__device__ __forceinline__ float bslot(bf16x8 f, int j){
  return __uint_as_float(((unsigned)(unsigned short)f[j]) << 16);
}

// asymmetric MFMA-test reference matrices
__device__ __forceinline__ double Aref(int i, int k){ return 0.5 + 0.03*i - 0.7*k + 0.011*i*k; }
__device__ __forceinline__ double Bref(int k, int j){ return 1.1*k - 0.17*j + 0.019*j*k + 0.23; }
__device__ __forceinline__ int Aint(int i, int k){ return ((i*5 + k*3) % 13) - 6; }
__device__ __forceinline__ int Bint(int k, int j){ return ((k*7 + j*11) % 17) - 8; }

// ---------------- S0 (1024 thr): keys + T + gates + calibrations + nbeta ----------------
__global__ __launch_bounds__(1024) void s0_kernel(unsigned* __restrict__ wsu, float log_ratio,
                          const float* __restrict__ invt){
#pragma clang fp contract(off)
  __shared__ int sbad, sbadc, sbadt;
  int t = threadIdx.x;
  if (t == 0){ sbad = 0; sbadc = 0; sbadt = 0; }
  __syncthreads();

  {
    int bad = 0;
    for (int i = 0; i < 64; ++i){
      int idx = t * 64 + i;
      double x = -20.0 + 40.0 * ((double)idx + 0.5) / 65536.0;
      double a = tanh_fast(x);
      double b = tanh(x);
      if ((float)a != (float)b) bad = 1;
      long long ia = __double_as_longlong(a), ib = __double_as_longlong(b);
      long long d = ia - ib; if (d < 0) d = -d;
      if (d > 8) bad = 1;
    }
    if (bad) atomicOr(&sbad, 1);
  }

  {
    float xv[8];
    #pragma unroll
    for (int p=0;p<8;++p){
      unsigned idx = (unsigned)(t*8+p);
      unsigned mant = (idx * 2654435761u) & 0x7FFFFFu;
      unsigned ex = 127u + (idx*7u)%8u - 4u;
      unsigned sgn = (idx & 1u) << 31;
      xv[p] = __uint_as_float(sgn | (ex<<23) | mant);
    }
    bf16x8 h,m,l;
    int badc=0, badt=0;
    split8<true>(xv,h,m,l);
    #pragma unroll
    for (int p=0;p<8;++p){
      double s = (double)bslot(h,p)+(double)bslot(m,p)+(double)bslot(l,p);
      if (s != (double)xv[p]) badc=1;
      if (fabsf(bslot(m,p)) > fabsf(xv[p])*0.00784f) badc=1;
    }
    split8<false>(xv,h,m,l);
    #pragma unroll
    for (int p=0;p<8;++p){
      double s = (double)bslot(h,p)+(double)bslot(m,p)+(double)bslot(l,p);
      if (s != (double)xv[p]) badt=1;
    }
    if (badc) atomicOr(&sbadc, 1);
    if (badt) atomicOr(&sbadt, 1);
  }

  if (t < 64){
    int l = t;
    int lr = l & 15, g = l >> 4;
    {
      double aval = Aref(lr, g);
      double bval = Bref(g, lr);
      int found = 8;
      for (int combo = 0; combo < 8; ++combo){
        int swap = combo & 1, drow = (combo>>1)&1, dt = (combo>>2)&1;
        f64x4 c = {0.0,0.0,0.0,0.0};
        if (swap) c = __builtin_amdgcn_mfma_f64_16x16x4f64(bval, aval, c, 0,0,0);
        else      c = __builtin_amdgcn_mfma_f64_16x16x4f64(aval, bval, c, 0,0,0);
        int bad = 0;
        #pragma unroll
        for (int r=0;r<4;++r){
          int f = drow ? (g + 4*r) : (4*g + r);
          int row = dt ? lr : f;
          int col = dt ? f  : lr;
          double e = 0.0;
          #pragma unroll
          for (int k=0;k<4;++k) e += Aref(row,k)*Bref(k,col);
          if (fabs(c[r] - e) > 1e-9) bad = 1;
        }
        if (__ballot(bad != 0) == 0ull){ found = combo; break; }
      }
      if (l == 0) wsu[503] = (unsigned)found;
    }
    {
      bf16x8 af, bf;
      #pragma unroll
      for (int j=0;j<8;++j){
        af[j] = (short)(__float_as_uint((float)Aint(lr, g*8+j)) >> 16);
        bf[j] = (short)(__float_as_uint((float)Bint(g*8+j, lr)) >> 16);
      }
      int found = 8;
      for (int combo = 0; combo < 8; ++combo){
        int swap = combo & 1, drow = (combo>>1)&1, dt = (combo>>2)&1;
        f32x4 c = {0.f,0.f,0.f,0.f};
        if (swap) c = __builtin_amdgcn_mfma_f32_16x16x32_bf16(bf, af, c, 0,0,0);
        else      c = __builtin_amdgcn_mfma_f32_16x16x32_bf16(af, bf, c, 0,0,0);
        int bad = 0;
        #pragma unroll
        for (int r=0;r<4;++r){
          int f = drow ? (g + 4*r) : (4*g + r);
          int row = dt ? lr : f;
          int col = dt ? f  : lr;
          int e = 0;
          for (int k=0;k<32;++k) e += Aint(row,k)*Bint(k,col);
          if (c[r] != (float)e) bad = 1;
        }
        if (__ballot(bad != 0) == 0ull){ found = combo; break; }
      }
      if (l == 0) wsu[506] = (unsigned)found;
    }
  }
  __syncthreads();
  if (t == 0){
    wsu[504] = (unsigned)sbad;
    wsu[507] = sbadc ? (sbadt ? 2u : 1u) : 0u;
  }

  uint32_t ka = 0u, kb = 1u;  // jax.random.key(1) == (0,1)
  uint32_t kinit0, kinit1, kl0, kl1;
#if RNG_PART
  { uint32_t a0=0u,a1=0u; tf_block(ka,kb,a0,a1); kinit0=a0; kinit1=a1; }
  { uint32_t a0=0u,a1=1u; tf_block(ka,kb,a0,a1); kl0=a0; kl1=a1; }
#else
  { uint32_t c00=0u,c01=2u; tf_block(ka,kb,c00,c01);
    uint32_t c10=1u,c11=3u; tf_block(ka,kb,c10,c11);
    kinit0=c00; kinit1=c10; kl0=c01; kl1=c11; }
#endif
  if (t == 0){
    wsu[502] = (unsigned)run_kats();
    wsu[505] = __float_as_uint(-(float)log1p(exp((double)invt[0])));  // -softplus
#if RNG_PART
    uint32_t x0=0u, x1=1u; tf_block(kinit0,kinit1,x0,x1);
    wsu[500]=x0; wsu[501]=x1;
#else
    uint32_t e00=0u,e01=2u; tf_block(kinit0,kinit1,e00,e01);
    uint32_t e10=1u,e11=3u; tf_block(kinit0,kinit1,e10,e11);
    wsu[500]=e01; wsu[501]=e11;
#endif
  }
  if (t < 100){
    uint32_t kt0=0u, kt1=(uint32_t)t; tf_block(kl0,kl1,kt0,kt1);   // fold_in(kloop, t)
    uint32_t q0, q1, v0, v1;
#if RNG_PART
    uint32_t p0=0u,p1=0u; tf_block(kt0,kt1,p0,p1);
    uint32_t u0=0u,u1=1u; tf_block(kt0,kt1,u0,u1);
    { uint32_t a=0u,b=1u; tf_block(p0,p1,a,b); q0=a; q1=b; }
    { uint32_t a=0u,b=1u; tf_block(u0,u1,a,b); v0=a; v1=b; }
#else
    uint32_t d00=0u,d01=2u; tf_block(kt0,kt1,d00,d01);
    uint32_t d10=1u,d11=3u; tf_block(kt0,kt1,d10,d11);
    uint32_t kp0=d00, kp1=d10, ku0=d01, ku1k=d11;
    uint32_t e00=0u,e01=2u; tf_block(kp0,kp1,e00,e01);
    uint32_t e10=1u,e11=3u; tf_block(kp0,kp1,e10,e11);
    q0=e01; q1=e11;
    { uint32_t a=0u,b=1u; tf_block(ku0,ku1k,a,b); v0=a; v1=b; }
#endif
    float fr = (float)t / 99.0f;
    float arg = log_ratio * fr;
    float T = (float)exp((double)arg);
    wsu[t*5+0]=q0; wsu[t*5+1]=q1; wsu[t*5+2]=v0; wsu[t*5+3]=v1;
    wsu[t*5+4]=__float_as_uint(T);
  }
}

// ---------------- BSPLIT: We -> interleaved bf16 h/m/l, layout [kg][col] bf16x8 ----------------
__global__ __launch_bounds__(256) void bsplit_kernel(
    const float* __restrict__ We, const unsigned* __restrict__ wsu,
    bf16x8* __restrict__ Bh, bf16x8* __restrict__ Bm, bf16x8* __restrict__ Bl){
#pragma clang fp contract(off)
  int kg = blockIdx.x;
  int col = threadIdx.x;
  float v[8];
  #pragma unroll
  for (int i=0;i<8;++i)
    v[i] = We[(size_t)(kg*8+i)*H_N + col];
  bf16x8 h, m, l;
  if (wsu[507] == 0u) split8<true >(v, h, m, l);
  else                split8<false>(v, h, m, l);
  size_t o = (size_t)kg*H_N + col;
  Bh[o] = h; Bm[o] = m; Bl[o] = l;
}

// ---------------- bf16-split GEMM: DOUBLE-BUFFERED LDS A split + pre-split B ----------------
// One barrier per 128-k superstrip; next-x loads issued after first kgl group (B loads
// drain first — r19 queue-order lesson), covered by remaining compute. Split values,
// MFMA chain order, chunk points identical to r22/r23 => energies bit-identical.
template<bool SWAP, bool CV>
__device__ __forceinline__ void bf16_gemm_dbuf(
    const float* __restrict__ x,
    const bf16x8* __restrict__ Bh, const bf16x8* __restrict__ Bm, const bf16x8* __restrict__ Bl,
    bf16x8* A0h, bf16x8* A0m, bf16x8* A0l,
    bf16x8* A1h, bf16x8* A1m, bf16x8* A1l,
    f32x4 c8[2][2], double hh64[2][2][4],
    int tid, int wave, int lr, int lk, int row0)
{
  f32x4 hh[2][2];
  #pragma unroll
  for (int rt=0;rt<2;++rt)
    #pragma unroll
    for (int j=0;j<2;++j){
      hh[rt][j] = (f32x4){0.f,0.f,0.f,0.f};
      c8[rt][j] = (f32x4){0.f,0.f,0.f,0.f};
      #pragma unroll
      for (int r=0;r<4;++r) hh64[rt][j][r] = 0.0;
    }

#define MMB(a,b,c) (SWAP ? __builtin_amdgcn_mfma_f32_16x16x32_bf16((b),(a),(c),0,0,0) \
                         : __builtin_amdgcn_mfma_f32_16x16x32_bf16((a),(b),(c),0,0,0))

  const int col0 = wave*32 + lr;
  const int col1 = col0 + 16;
  const int srow = tid >> 4;           // 0..31 staging row
  const int skg  = tid & 15;           // 0..15 staging kg within superstrip
  const float* xp = x + (size_t)(row0 + srow)*V_N + skg*8;
  const int sidx = skg*33 + srow;

  // prologue: stage ss=0 into buf0
  {
    float v[8];
    *(float4*)(v)   = *(const float4*)(xp);
    *(float4*)(v+4) = *(const float4*)(xp + 4);
    bf16x8 h, m, l;
    split8<CV>(v, h, m, l);
    A0h[sidx] = h; A0m[sidx] = m; A0l[sidx] = l;
  }
  __syncthreads();

  float vn[8];
  for (int ss=0; ss<NSS; ++ss){
    bf16x8* Ah_ = (ss & 1) ? A1h : A0h;
    bf16x8* Am_ = (ss & 1) ? A1m : A0m;
    bf16x8* Al_ = (ss & 1) ? A1l : A0l;
    bf16x8* Nh_ = (ss & 1) ? A0h : A1h;
    bf16x8* Nm_ = (ss & 1) ? A0m : A1m;
    bf16x8* Nl_ = (ss & 1) ? A0l : A1l;

    #pragma unroll
    for (int half=0; half<2; ++half){
      #pragma unroll
      for (int kin2=0; kin2<2; ++kin2){
        const int kgl = (half*2 + kin2)*4 + lk;
        const int kg  = ss*16 + kgl;
        const size_t bbase = (size_t)kg*H_N;
        bf16x8 bh0 = Bh[bbase + col0];
        bf16x8 bm0 = Bm[bbase + col0];
        bf16x8 bl0 = Bl[bbase + col0];
        bf16x8 bh1 = Bh[bbase + col1];
        bf16x8 bm1 = Bm[bbase + col1];
        bf16x8 bl1 = Bl[bbase + col1];
        bf16x8 ah[2], am[2], al[2];
        ah[0] = Ah_[kgl*33 + lr];      am[0] = Am_[kgl*33 + lr];      al[0] = Al_[kgl*33 + lr];
        ah[1] = Ah_[kgl*33 + 16 + lr]; am[1] = Am_[kgl*33 + 16 + lr]; al[1] = Al_[kgl*33 + 16 + lr];
        #pragma unroll
        for (int rt=0;rt<2;++rt){
          hh[rt][0] = MMB(ah[rt], bh0, hh[rt][0]);
          c8[rt][0] = MMB(ah[rt], bm0, c8[rt][0]);
          c8[rt][0] = MMB(am[rt], bh0, c8[rt][0]);
          c8[rt][0] = MMB(ah[rt], bl0, c8[rt][0]);
          c8[rt][0] = MMB(am[rt], bm0, c8[rt][0]);
          c8[rt][0] = MMB(al[rt], bh0, c8[rt][0]);
          hh[rt][1] = MMB(ah[rt], bh1, hh[rt][1]);
          c8[rt][1] = MMB(ah[rt], bm1, c8[rt][1]);
          c8[rt][1] = MMB(am[rt], bh1, c8[rt][1]);
          c8[rt][1] = MMB(ah[rt], bl1, c8[rt][1]);
          c8[rt][1] = MMB(am[rt], bm1, c8[rt][1]);
          c8[rt][1] = MMB(al[rt], bh1, c8[rt][1]);
        }
        // issue next-superstrip x loads AFTER the first group's B loads (queue order)
        if (half == 0 && kin2 == 0 && ss+1 < NSS){
          *(float4*)(vn)   = *(const float4*)(xp + (ss+1)*128);
          *(float4*)(vn+4) = *(const float4*)(xp + (ss+1)*128 + 4);
        }
      }
      // chunk hh -> f64 per 64-k half (matches r22/r23 chunk points)
      #pragma unroll
      for (int rt=0;rt<2;++rt)
        #pragma unroll
        for (int j=0;j<2;++j){
          #pragma unroll
          for (int r=0;r<4;++r) hh64[rt][j][r] += (double)hh[rt][j][r];
          hh[rt][j] = (f32x4){0.f,0.f,0.f,0.f};
        }
    }

    // stage next superstrip into the other buffer (loads long since landed)
    if (ss+1 < NSS){
      bf16x8 h, m, l;
      split8<CV>(vn, h, m, l);
      Nh_[sidx] = h; Nm_[sidx] = m; Nl_[sidx] = l;
    }
    __syncthreads();   // single barrier: next buf ready AND all cur reads complete
  }
#undef MMB
}

// ---------------- inline-split bf16 GEMM (r16/r20 fallback, no ws needed) ----------------
template<bool SWAP, bool CV>
__device__ __forceinline__ void bf16_gemm(
    const float* __restrict__ x, const float* __restrict__ We,
    f32x4 c8[2][2], double hh64[2][2][4],
    int wave, int lr, int lk, int row0)
{
  f32x4 hh[2][2];
  #pragma unroll
  for (int rt=0;rt<2;++rt)
    #pragma unroll
    for (int j=0;j<2;++j){
      hh[rt][j] = (f32x4){0.f,0.f,0.f,0.f};
      c8[rt][j] = (f32x4){0.f,0.f,0.f,0.f};
      #pragma unroll
      for (int r=0;r<4;++r) hh64[rt][j][r] = 0.0;
    }

#define MMB(a,b,c) (SWAP ? __builtin_amdgcn_mfma_f32_16x16x32_bf16((b),(a),(c),0,0,0) \
                         : __builtin_amdgcn_mfma_f32_16x16x32_bf16((a),(b),(c),0,0,0))

  const float* xr0 = x + (size_t)(row0 + lr)*V_N + lk*8;
  const float* xr1 = x + (size_t)(row0 + 16 + lr)*V_N + lk*8;

  for (int s=0; s<NSTRIP; ++s){
    #pragma unroll
    for (int kin=0;kin<2;++kin){
      float bv0[8], bv1[8];
      const float* bp = We + ((size_t)(s*KT + kin*32 + lk*8))*H_N + wave*32 + lr;
      #pragma unroll
      for (int jj=0;jj<8;++jj){ bv0[jj] = bp[(size_t)jj*H_N]; bv1[jj] = bp[(size_t)jj*H_N + 16]; }
      bf16x8 bh0,bm0,bl0,bh1,bm1,bl1;
      split8<CV>(bv0, bh0, bm0, bl0);
      split8<CV>(bv1, bh1, bm1, bl1);
      bf16x8 ah[2], am[2], al[2];
      float av[8];
      *(float4*)(av)   = *(const float4*)(xr0 + s*KT + kin*32);
      *(float4*)(av+4) = *(const float4*)(xr0 + s*KT + kin*32 + 4);
      split8<CV>(av, ah[0], am[0], al[0]);
      *(float4*)(av)   = *(const float4*)(xr1 + s*KT + kin*32);
      *(float4*)(av+4) = *(const float4*)(xr1 + s*KT + kin*32 + 4);
      split8<CV>(av, ah[1], am[1], al[1]);
      #pragma unroll
      for (int rt=0;rt<2;++rt){
        hh[rt][0] = MMB(ah[rt], bh0, hh[rt][0]);
        c8[rt][0] = MMB(ah[rt], bm0, c8[rt][0]);
        c8[rt][0] = MMB(am[rt], bh0, c8[rt][0]);
        c8[rt][0] = MMB(ah[rt], bl0, c8[rt][0]);
        c8[rt][0] = MMB(am[rt], bm0, c8[rt][0]);
        c8[rt][0] = MMB(al[rt], bh0, c8[rt][0]);
        hh[rt][1] = MMB(ah[rt], bh1, hh[rt][1]);
        c8[rt][1] = MMB(ah[rt], bm1, c8[rt][1]);
        c8[rt][1] = MMB(am[rt], bh1, c8[rt][1]);
        c8[rt][1] = MMB(ah[rt], bl1, c8[rt][1]);
        c8[rt][1] = MMB(am[rt], bm1, c8[rt][1]);
        c8[rt][1] = MMB(al[rt], bh1, c8[rt][1]);
      }
    }
    #pragma unroll
    for (int rt=0;rt<2;++rt)
      #pragma unroll
      for (int j=0;j<2;++j){
        #pragma unroll
        for (int r=0;r<4;++r) hh64[rt][j][r] += (double)hh[rt][j][r];
        hh[rt][j] = (f32x4){0.f,0.f,0.f,0.f};
      }
  }
#undef MMB
}

// ---------------- VALU GEMM fallback ----------------
__device__ __forceinline__ void valu_gemm_and_enc(
    const float* __restrict__ x, const float* __restrict__ We, const float* __restrict__ be,
    float* enc_s, int tid, int row0, unsigned slowtanh)
{
  const int rg = tid >> 6;
  const int c0 = (tid & 63) * 4;
  double acc[4][4];
  #pragma unroll
  for (int r=0;r<4;++r){ acc[r][0]=0.0; acc[r][1]=0.0; acc[r][2]=0.0; acc[r][3]=0.0; }

  for (int v=0; v<V_N; ++v){
    const float* wp = We + (size_t)v*H_N + c0;
    double w0=(double)wp[0], w1=(double)wp[1], w2d=(double)wp[2], w3=(double)wp[3];
    #pragma unroll
    for (int r4=0;r4<4;++r4){
      double xv = (double)x[(size_t)(row0+rg*4+r4)*V_N + v];
      acc[r4][0] = fma(xv, w0, acc[r4][0]);
      acc[r4][1] = fma(xv, w1, acc[r4][1]);
      acc[r4][2] = fma(xv, w2d, acc[r4][2]);
      acc[r4][3] = fma(xv, w3, acc[r4][3]);
    }
  }
  #pragma unroll
  for (int r4=0;r4<4;++r4){
    int r = rg*4 + r4;
    #pragma unroll
    for (int j=0;j<4;++j){
      int c = c0 + j;
      float m1 = (float)(acc[r4][j] + (double)be[c]);
      enc_s[r*257 + c] = (float)tanh_d((double)m1, slowtanh);
    }
  }
}

// ---------------- KE: energies + logits (dbuf GEMM; sampler separate) ----------------
__global__ __launch_bounds__(512) void ke_kernel(
    const float* __restrict__ x, const float* __restrict__ We,
    const float* __restrict__ be, const float* __restrict__ W1,
    const float* __restrict__ b1, const float* __restrict__ w2,
    const float* __restrict__ b2, const float* __restrict__ invt,
    const unsigned* __restrict__ wsu,
    const bf16x8* __restrict__ Bh, const bf16x8* __restrict__ Bm,
    const bf16x8* __restrict__ Bl, int presplit,
    float* __restrict__ energ, float* __restrict__ logit){
#pragma clang fp contract(off)
  __shared__ float smemf[12800];            // 51.2 KB: dbuf A (6 x 528 bf16x8); enc_s aliases
  __shared__ double t2p[BROWS*4*4];
  __shared__ float t2_s[BROWS*4];
  float* enc_s = smemf;
  bf16x8* A0h = (bf16x8*)smemf;             // 528 entries each (16*33)
  bf16x8* A0m = A0h + 528;
  bf16x8* A0l = A0m + 528;
  bf16x8* A1h = A0l + 528;
  bf16x8* A1m = A1h + 528;
  bf16x8* A1l = A1m + 528;

  const int tid = threadIdx.x;
  const int wave = tid >> 6;
  const int l = tid & 63;
  const int lr = l & 15;
  const int lk = l >> 4;
  const int row0 = blockIdx.x * BROWS;

  const unsigned combo64 = wsu[503];
  const unsigned combo16 = wsu[506];
  const unsigned splmode = wsu[507];
  const unsigned slowtanh = wsu[504];
  const float nbeta = __uint_as_float(wsu[505]);

  if (combo16 < 8u && splmode < 2u){
    f32x4 c8[2][2];
    double hh64[2][2][4];
    const bool sw = (combo16 & 1u);
    if (presplit){
      if (splmode == 0u){
        if (sw) bf16_gemm_dbuf<true ,true >(x, Bh, Bm, Bl, A0h,A0m,A0l, A1h,A1m,A1l, c8, hh64, tid, wave, lr, lk, row0);
        else    bf16_gemm_dbuf<false,true >(x, Bh, Bm, Bl, A0h,A0m,A0l, A1h,A1m,A1l, c8, hh64, tid, wave, lr, lk, row0);
      } else {
        if (sw) bf16_gemm_dbuf<true ,false>(x, Bh, Bm, Bl, A0h,A0m,A0l, A1h,A1m,A1l, c8, hh64, tid, wave, lr, lk, row0);
        else    bf16_gemm_dbuf<false,false>(x, Bh, Bm, Bl, A0h,A0m,A0l, A1h,A1m,A1l, c8, hh64, tid, wave, lr, lk, row0);
      }
    } else if (splmode == 0u){
      if (sw) bf16_gemm<true ,true >(x, We, c8, hh64, wave, lr, lk, row0);
      else    bf16_gemm<false,true >(x, We, c8, hh64, wave, lr, lk, row0);
    } else {
      if (sw) bf16_gemm<true ,false>(x, We, c8, hh64, wave, lr, lk, row0);
      else    bf16_gemm<false,false>(x, We, c8, hh64, wave, lr, lk, row0);
    }
    __syncthreads();
    const int drow = (combo16 >> 1) & 1, dt = (combo16 >> 2) & 1;
    #pragma unroll
    for (int rt=0;rt<2;++rt){
      #pragma unroll
      for (int j=0;j<2;++j){
        #pragma unroll
        for (int r=0;r<4;++r){
          int f = drow ? (lk + 4*r) : (4*lk + r);
          int m = dt ? lr : f;
          int n = dt ? f  : lr;
          int row = rt*16 + m;
          int col = wave*32 + j*16 + n;
          double tot = hh64[rt][j][r] + (double)c8[rt][j][r] + (double)be[col];
          float m1 = (float)tot;                                  // f32 boundary
          enc_s[row*257 + col] = (float)tanh_d((double)m1, slowtanh);
        }
      }
    }
  } else {
    valu_gemm_and_enc(x, We, be, enc_s, tid, row0, slowtanh);
  }
  __syncthreads();

  // t2 = enc @ W1e: 32 rows x 4 q x 4 segs(64) = 512 threads, fixed combine order
  {
    int r = tid >> 4, q = (tid >> 2) & 3, seg = tid & 3;
    double s = 0.0;
    const float* er = enc_s + r*257 + seg*64;
    const float* wq = W1 + seg*64*4 + q;
    #pragma unroll 8
    for (int hh=0; hh<64; ++hh)
      s = fma((double)er[hh], (double)wq[hh*4], s);
    t2p[(r*4+q)*4 + seg] = s;
  }
  __syncthreads();
  if (tid < 128){
    double s = ((t2p[tid*4+0] + t2p[tid*4+1]) + t2p[tid*4+2]) + t2p[tid*4+3];
    t2_s[tid] = (float)s;
  }
  __syncthreads();

  {
    int r = tid >> 4, e = tid & 15;
    float y = 0.0f;
    #pragma unroll
    for (int q=0;q<4;++q){
      float a1f = t2_s[r*4+q] + W1[(H_N+e)*4+q];
      float a2f = a1f + b1[q];
      float hin  = (float)tanh_d((double)a2f, slowtanh);
      float hout = (float)tanh_d((double)hin, slowtanh);
      y = y + hout * w2[q];
    }
    float yb = y + b2[0];
    float en = 3.0f * (float)tanh_d((double)yb, slowtanh);
    size_t gi = (size_t)(row0 + r)*E_N + e;
    energ[gi] = en;
    logit[gi] = nbeta * en;
  }
}

// ---------------- SAMP: annealed Metropolis chains (256 blocks x 128 thr; proven) ----------------
__global__ __launch_bounds__(128) void samp_kernel(
    const float* __restrict__ energ, const unsigned* __restrict__ wsu,
    float* __restrict__ probs){
#pragma clang fp contract(off)
  __shared__ float se[128*16];
  const int lt = threadIdx.x;
  const int b = blockIdx.x*128 + lt;

  unsigned flag = wsu[502];
  if (flag != 0u){
    float c = 0.10f + 0.05f * (float)flag;
    float* op = probs + (size_t)b*E_N;
    #pragma unroll
    for (int j0=0; j0<16; j0+=4){
      float4 r; r.x=c; r.y=c; r.z=c; r.w=c;
      *(float4*)(op + j0) = r;
    }
    return;
  }

  float4* sv = (float4*)(se + lt*16);
  const float4* er = (const float4*)(energ + (size_t)b*E_N);
  sv[0]=er[0]; sv[1]=er[1]; sv[2]=er[2]; sv[3]=er[3];

  uint32_t k20 = wsu[500], k21 = wsu[501];
  uint32_t cur = rbits(k20, k21, (uint32_t)b) & 15u;

  for (int t=0; t<100; ++t){
    uint32_t pa=wsu[t*5+0], pb=wsu[t*5+1], ua=wsu[t*5+2], ub=wsu[t*5+3];
    float T = __uint_as_float(wsu[t*5+4]);
    uint32_t prop = rbits(pa, pb, (uint32_t)b) & 15u;
    uint32_t ru   = rbits(ua, ub, (uint32_t)b);
    float u = __uint_as_float((ru >> 9) | 0x3f800000u) - 1.0f;
    float ec = se[lt*16 + (int)cur];
    float ep = se[lt*16 + (int)prop];
    float z = (-(ep - ec)) / T;
    z = fminf(z, 0.0f);
    float a = (float)exp((double)z);     // correctly-rounded f32 exp
    cur = (u < a) ? prop : cur;
  }
  float* op = probs + (size_t)b*E_N;
  #pragma unroll
  for (int j0=0; j0<16; j0+=4){
    float4 r;
    r.x = (cur == (uint32_t)(j0+0)) ? 1.0f : 0.0f;
    r.y = (cur == (uint32_t)(j0+1)) ? 1.0f : 0.0f;
    r.z = (cur == (uint32_t)(j0+2)) ? 1.0f : 0.0f;
    r.w = (cur == (uint32_t)(j0+3)) ? 1.0f : 0.0f;
    *(float4*)(op + j0) = r;
  }
}

extern "C" void kernel_launch(void* const* d_in, const int* in_sizes, int n_in,
                              void* d_out, int out_size, void* d_ws, size_t ws_size,
                              hipStream_t stream) {
  const float* x   = (const float*)d_in[0];
  const float* We  = (const float*)d_in[1];
  const float* be  = (const float*)d_in[2];
  const float* W1  = (const float*)d_in[3];
  const float* b1  = (const float*)d_in[4];
  const float* w2  = (const float*)d_in[5];
  const float* b2  = (const float*)d_in[6];
  const float* itp = (const float*)d_in[7];
  float* out = (float*)d_out;
  float* probs = out;
  float* energ = out + (size_t)B_N*E_N;
  float* logit = out + 2*(size_t)B_N*E_N;
  unsigned* wsu = (unsigned*)d_ws;

  // workspace: 4KB header | Bh,Bm,Bl (1MB each)
  const size_t bsz = (size_t)KG_N * H_N * 16;
  const size_t need = 4096 + 3*bsz;
  int presplit = (ws_size >= need) ? 1 : 0;
  char* base = (char*)d_ws + 4096;
  bf16x8* Bh = (bf16x8*)(base);
  bf16x8* Bm = (bf16x8*)(base + bsz);
  bf16x8* Bl = (bf16x8*)(base + 2*bsz);

  float log_ratio = (float)log((double)((float)0.1));

  hipLaunchKernelGGL(s0_kernel, dim3(1), dim3(1024), 0, stream, wsu, log_ratio, itp);
  if (presplit)
    hipLaunchKernelGGL(bsplit_kernel, dim3(KG_N), dim3(256), 0, stream, We, wsu, Bh, Bm, Bl);
  hipLaunchKernelGGL(ke_kernel, dim3(B_N/BROWS), dim3(512), 0, stream,
                     x, We, be, W1, b1, w2, b2, itp, wsu,
                     Bh, Bm, Bl, presplit,
                     energ, logit);
  hipLaunchKernelGGL(samp_kernel, dim3(B_N/128), dim3(128), 0, stream,
                     energ, wsu, probs);
}

// Round 25
// 431.663 us; speedup vs baseline: 1.0771x; 1.0771x over previous
//
#include <hip/hip_runtime.h>
#include <math.h>
#include <stdint.h>

#define B_N 32768
#define V_N 2048
#define H_N 256
#define E_N 16
#define Q_N 4

#define BROWS 32
#define KG_N (V_N/8)      // 256 k-groups
#define NSS (V_N/128)     // 16 superstrips

#define RNG_PART 1

typedef double f64x4 __attribute__((ext_vector_type(4)));
typedef float  f32x4 __attribute__((ext_vector_type(4)));
typedef short  bf16x8 __attribute__((ext_vector_type(8)));

union U8 { unsigned u[4]; bf16x8 v; };

// ---------------- Threefry2x32 (JAX-exact, 20 rounds; KAT-verified on HW r2) ----------------
#define TF_R(x0,x1,r) { x0 += x1; x1 = ((x1 << (r)) | (x1 >> (32-(r)))); x1 ^= x0; }

__device__ __forceinline__ void tf_block(uint32_t k0, uint32_t k1, uint32_t &x0, uint32_t &x1){
  uint32_t k2 = k0 ^ k1 ^ 0x1BD11BDAu;
  x0 += k0; x1 += k1;
  TF_R(x0,x1,13) TF_R(x0,x1,15) TF_R(x0,x1,26) TF_R(x0,x1,6)
  x0 += k1; x1 += k2 + 1u;
  TF_R(x0,x1,17) TF_R(x0,x1,29) TF_R(x0,x1,16) TF_R(x0,x1,24)
  x0 += k2; x1 += k0 + 2u;
  TF_R(x0,x1,13) TF_R(x0,x1,15) TF_R(x0,x1,26) TF_R(x0,x1,6)
  x0 += k0; x1 += k1 + 3u;
  TF_R(x0,x1,17) TF_R(x0,x1,29) TF_R(x0,x1,16) TF_R(x0,x1,24)
  x0 += k1; x1 += k2 + 4u;
  TF_R(x0,x1,13) TF_R(x0,x1,15) TF_R(x0,x1,26) TF_R(x0,x1,6)
  x0 += k2; x1 += k0 + 5u;
}

__device__ __forceinline__ int run_kats(){
  uint32_t x0, x1;
  x0 = 0u; x1 = 0u;
  tf_block(0u, 0u, x0, x1);
  if (x0 != 0x6b200159u || x1 != 0x99ba4efeu) return 1;
  x0 = 0xFFFFFFFFu; x1 = 0xFFFFFFFFu;
  tf_block(0xFFFFFFFFu, 0xFFFFFFFFu, x0, x1);
  if (x0 != 0x1cb996fcu || x1 != 0xbb002be7u) return 2;
  x0 = 0x243f6a88u; x1 = 0x85a308d3u;
  tf_block(0x13198a2eu, 0x03707344u, x0, x1);
  if (x0 != 0xc4923a9cu || x1 != 0x483df7a0u) return 3;
  return 0;
}

__device__ __forceinline__ uint32_t rbits(uint32_t ka, uint32_t kb, uint32_t b){
#if RNG_PART
  uint32_t x0 = 0u, x1 = b;
  tf_block(ka, kb, x0, x1);
  return x0 ^ x1;
#else
  uint32_t i = b & 16383u;
  uint32_t x0 = i, x1 = i + 16384u;
  tf_block(ka, kb, x0, x1);
  return (b < 16384u) ? x0 : x1;
#endif
}

// ---------------- fast f64 tanh (~3 ulp), HW-gated vs libm ----------------
__device__ __forceinline__ double exp_pos_f64(double v){
  const double LOG2E  = 1.4426950408889634074;
  const double LN2HI  = 6.93147180369123816490e-01;
  const double LN2LO  = 1.90821492927058770002e-10;
  double k = rint(v * LOG2E);
  double r = fma(-k, LN2HI, v);
  r = fma(-k, LN2LO, r);
  double p = 1.6059043836821613e-10;
  p = fma(p, r, 2.08767569878681e-09);
  p = fma(p, r, 2.505210838544172e-08);
  p = fma(p, r, 2.7557319223985893e-07);
  p = fma(p, r, 2.755731922398589e-06);
  p = fma(p, r, 2.48015873015873e-05);
  p = fma(p, r, 1.984126984126984e-04);
  p = fma(p, r, 1.3888888888888889e-03);
  p = fma(p, r, 8.333333333333333e-03);
  p = fma(p, r, 4.1666666666666664e-02);
  p = fma(p, r, 1.6666666666666666e-01);
  p = fma(p, r, 5.0e-01);
  p = fma(p, r, 1.0);
  p = fma(p, r, 1.0);
  int n = (int)k;
  double sc = __longlong_as_double(((long long)(1023 + n)) << 52);
  return p * sc;
}

__device__ __forceinline__ double tanh_fast(double x){
  double ax = fabs(x);
  if (ax < 0.25){
    double z = x * x;
    double p = 9.691537956929451e-05;
    p = fma(p, z, -2.3912911424355248e-04);
    p = fma(p, z,  5.900274409455859e-04);
    p = fma(p, z, -1.4558343870513183e-03);
    p = fma(p, z,  3.592128036572481e-03);
    p = fma(p, z, -8.863235529902197e-03);
    p = fma(p, z,  2.1869488536155203e-02);
    p = fma(p, z, -5.396825396825397e-02);
    p = fma(p, z,  1.3333333333333333e-01);
    p = fma(p, z, -3.3333333333333333e-01);
    double q = fma(p, z, 1.0);
    return x * q;
  }
  if (ax > 19.0) return copysign(1.0, x);
  double y = exp_pos_f64(2.0 * ax);
  double t = 1.0 - 2.0/(y + 1.0);
  return copysign(t, x);
}

__device__ __forceinline__ double tanh_d(double x, unsigned slow){
  return slow ? tanh(x) : tanh_fast(x);
}

// ---------------- exact 3-way bf16 split ----------------
__device__ __forceinline__ unsigned cvt_pk_bf16(float a, float b){
  unsigned r;
  asm("v_cvt_pk_bf16_f32 %0, %1, %2" : "=v"(r) : "v"(a), "v"(b));
  return r;
}

template<bool CV>
__device__ __forceinline__ void splitpair(float a, float b, unsigned &uh, unsigned &um, unsigned &ul){
  float ha, hb, ma, mb;
  if (CV){
    uh = cvt_pk_bf16(a, b);
    ha = __uint_as_float(uh<<16); hb = __uint_as_float(uh & 0xFFFF0000u);
  } else {
    unsigned ua=__float_as_uint(a), ub=__float_as_uint(b);
    uh = (ua>>16) | (ub & 0xFFFF0000u);
    ha = __uint_as_float(ua & 0xFFFF0000u); hb = __uint_as_float(ub & 0xFFFF0000u);
  }
  float ra = a - ha, rb = b - hb;
  if (CV){
    um = cvt_pk_bf16(ra, rb);
    ma = __uint_as_float(um<<16); mb = __uint_as_float(um & 0xFFFF0000u);
  } else {
    unsigned va=__float_as_uint(ra), vb=__float_as_uint(rb);
    um = (va>>16) | (vb & 0xFFFF0000u);
    ma = __uint_as_float(va & 0xFFFF0000u); mb = __uint_as_float(vb & 0xFFFF0000u);
  }
  float sa = ra - ma, sb = rb - mb;
  if (CV) ul = cvt_pk_bf16(sa, sb);
  else    ul = (__float_as_uint(sa)>>16) | (__float_as_uint(sb) & 0xFFFF0000u);
}

template<bool CV>
__device__ __forceinline__ void split8(const float* v, bf16x8& fh, bf16x8& fm, bf16x8& fl){
  U8 H, M, L;
  #pragma unroll
  for (int p=0;p<4;++p)
    splitpair<CV>(v[2*p], v[2*p+1], H.u[p], M.u[p], L.u[p]);
  fh=H.v; fm=M.v; fl=L.v;
}

__device__ __forceinline__ float bslot(bf16x8 f, int j){
  return __uint_as_float(((unsigned)(unsigned short)f[j]) << 16);
}

// split-gate test value for global index idx (deterministic, HW-independent)
__device__ __forceinline__ float gate_val(unsigned idx){
  unsigned mant = (idx * 2654435761u) & 0x7FFFFFu;
  unsigned ex = 127u + (idx*7u)%8u - 4u;
  unsigned sgn = (idx & 1u) << 31;
  return __uint_as_float(sgn | (ex<<23) | mant);
}

// asymmetric MFMA-test reference matrices
__device__ __forceinline__ double Aref(int i, int k){ return 0.5 + 0.03*i - 0.7*k + 0.011*i*k; }
__device__ __forceinline__ double Bref(int k, int j){ return 1.1*k - 0.17*j + 0.019*j*k + 0.23; }
__device__ __forceinline__ int Aint(int i, int k){ return ((i*5 + k*3) % 13) - 6; }
__device__ __forceinline__ int Bint(int k, int j){ return ((k*7 + j*11) % 17) - 8; }

// ---------------- INIT (65 blocks x 1024 thr): block0 = s0; blocks 1..64 = bsplit ----------------
__global__ __launch_bounds__(1024) void init_kernel(unsigned* __restrict__ wsu, float log_ratio,
    const float* __restrict__ invt, const float* __restrict__ We,
    bf16x8* __restrict__ Bh, bf16x8* __restrict__ Bm, bf16x8* __restrict__ Bl, int presplit){
#pragma clang fp contract(off)
  __shared__ int sbad, sbadc, sbadt;
  int t = threadIdx.x;
  if (t == 0){ sbad = 0; sbadc = 0; sbadt = 0; }
  __syncthreads();

  if (blockIdx.x != 0){
    // ---- bsplit with locally-recomputed (identical, deterministic) split gate ----
    if (!presplit) return;
    {
      float xv[8];
      #pragma unroll
      for (int p=0;p<8;++p) xv[p] = gate_val((unsigned)(t*8+p));
      bf16x8 h,m,l;
      int badc=0, badt=0;
      split8<true>(xv,h,m,l);
      #pragma unroll
      for (int p=0;p<8;++p){
        double s = (double)bslot(h,p)+(double)bslot(m,p)+(double)bslot(l,p);
        if (s != (double)xv[p]) badc=1;
        if (fabsf(bslot(m,p)) > fabsf(xv[p])*0.00784f) badc=1;
      }
      split8<false>(xv,h,m,l);
      #pragma unroll
      for (int p=0;p<8;++p){
        double s = (double)bslot(h,p)+(double)bslot(m,p)+(double)bslot(l,p);
        if (s != (double)xv[p]) badt=1;
      }
      if (badc) atomicOr(&sbadc, 1);
      if (badt) atomicOr(&sbadt, 1);
    }
    __syncthreads();
    unsigned spl = sbadc ? (sbadt ? 2u : 1u) : 0u;
    if (spl >= 2u) return;                       // ke will fall back (wsu[507]==2 too)
    int kg = (blockIdx.x - 1)*4 + (t >> 8);      // 4 kg per block
    int col = t & 255;
    float v[8];
    #pragma unroll
    for (int i=0;i<8;++i)
      v[i] = We[(size_t)(kg*8+i)*H_N + col];
    bf16x8 h, m, l;
    if (spl == 0u) split8<true >(v, h, m, l);
    else           split8<false>(v, h, m, l);
    size_t o = (size_t)kg*H_N + col;
    Bh[o] = h; Bm[o] = m; Bl[o] = l;
    return;
  }

  // ---- block 0: full s0 body (unchanged from r23) ----
  {
    int bad = 0;
    for (int i = 0; i < 64; ++i){
      int idx = t * 64 + i;
      double x = -20.0 + 40.0 * ((double)idx + 0.5) / 65536.0;
      double a = tanh_fast(x);
      double b = tanh(x);
      if ((float)a != (float)b) bad = 1;
      long long ia = __double_as_longlong(a), ib = __double_as_longlong(b);
      long long d = ia - ib; if (d < 0) d = -d;
      if (d > 8) bad = 1;
    }
    if (bad) atomicOr(&sbad, 1);
  }

  {
    float xv[8];
    #pragma unroll
    for (int p=0;p<8;++p) xv[p] = gate_val((unsigned)(t*8+p));
    bf16x8 h,m,l;
    int badc=0, badt=0;
    split8<true>(xv,h,m,l);
    #pragma unroll
    for (int p=0;p<8;++p){
      double s = (double)bslot(h,p)+(double)bslot(m,p)+(double)bslot(l,p);
      if (s != (double)xv[p]) badc=1;
      if (fabsf(bslot(m,p)) > fabsf(xv[p])*0.00784f) badc=1;
    }
    split8<false>(xv,h,m,l);
    #pragma unroll
    for (int p=0;p<8;++p){
      double s = (double)bslot(h,p)+(double)bslot(m,p)+(double)bslot(l,p);
      if (s != (double)xv[p]) badt=1;
    }
    if (badc) atomicOr(&sbadc, 1);
    if (badt) atomicOr(&sbadt, 1);
  }

  if (t < 64){
    int l = t;
    int lr = l & 15, g = l >> 4;
    {
      double aval = Aref(lr, g);
      double bval = Bref(g, lr);
      int found = 8;
      for (int combo = 0; combo < 8; ++combo){
        int swap = combo & 1, drow = (combo>>1)&1, dt = (combo>>2)&1;
        f64x4 c = {0.0,0.0,0.0,0.0};
        if (swap) c = __builtin_amdgcn_mfma_f64_16x16x4f64(bval, aval, c, 0,0,0);
        else      c = __builtin_amdgcn_mfma_f64_16x16x4f64(aval, bval, c, 0,0,0);
        int bad = 0;
        #pragma unroll
        for (int r=0;r<4;++r){
          int f = drow ? (g + 4*r) : (4*g + r);
          int row = dt ? lr : f;
          int col = dt ? f  : lr;
          double e = 0.0;
          #pragma unroll
          for (int k=0;k<4;++k) e += Aref(row,k)*Bref(k,col);
          if (fabs(c[r] - e) > 1e-9) bad = 1;
        }
        if (__ballot(bad != 0) == 0ull){ found = combo; break; }
      }
      if (l == 0) wsu[503] = (unsigned)found;
    }
    {
      bf16x8 af, bf;
      #pragma unroll
      for (int j=0;j<8;++j){
        af[j] = (short)(__float_as_uint((float)Aint(lr, g*8+j)) >> 16);
        bf[j] = (short)(__float_as_uint((float)Bint(g*8+j, lr)) >> 16);
      }
      int found = 8;
      for (int combo = 0; combo < 8; ++combo){
        int swap = combo & 1, drow = (combo>>1)&1, dt = (combo>>2)&1;
        f32x4 c = {0.f,0.f,0.f,0.f};
        if (swap) c = __builtin_amdgcn_mfma_f32_16x16x32_bf16(bf, af, c, 0,0,0);
        else      c = __builtin_amdgcn_mfma_f32_16x16x32_bf16(af, bf, c, 0,0,0);
        int bad = 0;
        #pragma unroll
        for (int r=0;r<4;++r){
          int f = drow ? (g + 4*r) : (4*g + r);
          int row = dt ? lr : f;
          int col = dt ? f  : lr;
          int e = 0;
          for (int k=0;k<32;++k) e += Aint(row,k)*Bint(k,col);
          if (c[r] != (float)e) bad = 1;
        }
        if (__ballot(bad != 0) == 0ull){ found = combo; break; }
      }
      if (l == 0) wsu[506] = (unsigned)found;
    }
  }
  __syncthreads();
  if (t == 0){
    wsu[504] = (unsigned)sbad;
    wsu[507] = sbadc ? (sbadt ? 2u : 1u) : 0u;
  }

  uint32_t ka = 0u, kb = 1u;  // jax.random.key(1) == (0,1)
  uint32_t kinit0, kinit1, kl0, kl1;
#if RNG_PART
  { uint32_t a0=0u,a1=0u; tf_block(ka,kb,a0,a1); kinit0=a0; kinit1=a1; }
  { uint32_t a0=0u,a1=1u; tf_block(ka,kb,a0,a1); kl0=a0; kl1=a1; }
#else
  { uint32_t c00=0u,c01=2u; tf_block(ka,kb,c00,c01);
    uint32_t c10=1u,c11=3u; tf_block(ka,kb,c10,c11);
    kinit0=c00; kinit1=c10; kl0=c01; kl1=c11; }
#endif
  if (t == 0){
    wsu[502] = (unsigned)run_kats();
    wsu[505] = __float_as_uint(-(float)log1p(exp((double)invt[0])));  // -softplus
#if RNG_PART
    uint32_t x0=0u, x1=1u; tf_block(kinit0,kinit1,x0,x1);
    wsu[500]=x0; wsu[501]=x1;
#else
    uint32_t e00=0u,e01=2u; tf_block(kinit0,kinit1,e00,e01);
    uint32_t e10=1u,e11=3u; tf_block(kinit0,kinit1,e10,e11);
    wsu[500]=e01; wsu[501]=e11;
#endif
  }
  if (t < 100){
    uint32_t kt0=0u, kt1=(uint32_t)t; tf_block(kl0,kl1,kt0,kt1);   // fold_in(kloop, t)
    uint32_t q0, q1, v0, v1;
#if RNG_PART
    uint32_t p0=0u,p1=0u; tf_block(kt0,kt1,p0,p1);
    uint32_t u0=0u,u1=1u; tf_block(kt0,kt1,u0,u1);
    { uint32_t a=0u,b=1u; tf_block(p0,p1,a,b); q0=a; q1=b; }
    { uint32_t a=0u,b=1u; tf_block(u0,u1,a,b); v0=a; v1=b; }
#else
    uint32_t d00=0u,d01=2u; tf_block(kt0,kt1,d00,d01);
    uint32_t d10=1u,d11=3u; tf_block(kt0,kt1,d10,d11);
    uint32_t kp0=d00, kp1=d10, ku0=d01, ku1k=d11;
    uint32_t e00=0u,e01=2u; tf_block(kp0,kp1,e00,e01);
    uint32_t e10=1u,e11=3u; tf_block(kp0,kp1,e10,e11);
    q0=e01; q1=e11;
    { uint32_t a=0u,b=1u; tf_block(ku0,ku1k,a,b); v0=a; v1=b; }
#endif
    float fr = (float)t / 99.0f;
    float arg = log_ratio * fr;
    float T = (float)exp((double)arg);
    wsu[t*5+0]=q0; wsu[t*5+1]=q1; wsu[t*5+2]=v0; wsu[t*5+3]=v1;
    wsu[t*5+4]=__float_as_uint(T);
  }
}

// ---------------- bf16-split GEMM: LDS-cooperative A split + pre-split B (r22/r23-proven) ----------------
template<bool SWAP, bool CV>
__device__ __forceinline__ void bf16_gemm_lds(
    const float* __restrict__ x,
    const bf16x8* __restrict__ Bh, const bf16x8* __restrict__ Bm, const bf16x8* __restrict__ Bl,
    bf16x8* Ahs, bf16x8* Ams, bf16x8* Als,
    f32x4 c8[2][2], double hh64[2][2][4],
    int tid, int wave, int lr, int lk, int row0)
{
  f32x4 hh[2][2];
  #pragma unroll
  for (int rt=0;rt<2;++rt)
    #pragma unroll
    for (int j=0;j<2;++j){
      hh[rt][j] = (f32x4){0.f,0.f,0.f,0.f};
      c8[rt][j] = (f32x4){0.f,0.f,0.f,0.f};
      #pragma unroll
      for (int r=0;r<4;++r) hh64[rt][j][r] = 0.0;
    }

#define MMB(a,b,c) (SWAP ? __builtin_amdgcn_mfma_f32_16x16x32_bf16((b),(a),(c),0,0,0) \
                         : __builtin_amdgcn_mfma_f32_16x16x32_bf16((a),(b),(c),0,0,0))

  const int col0 = wave*32 + lr;
  const int col1 = col0 + 16;
  const int srow = tid >> 4;           // 0..31 staging row
  const int skg  = tid & 15;           // 0..15 staging kg within superstrip
  const float* xp = x + (size_t)(row0 + srow)*V_N + skg*8;

  for (int ss=0; ss<NSS; ++ss){
    {
      float v[8];
      *(float4*)(v)   = *(const float4*)(xp + ss*128);
      *(float4*)(v+4) = *(const float4*)(xp + ss*128 + 4);
      bf16x8 h, m, l;
      split8<CV>(v, h, m, l);
      Ahs[skg*33 + srow] = h;
      Ams[skg*33 + srow] = m;
      Als[skg*33 + srow] = l;
    }
    __syncthreads();

    #pragma unroll
    for (int half=0; half<2; ++half){
      #pragma unroll
      for (int kin2=0; kin2<2; ++kin2){
        const int kgl = (half*2 + kin2)*4 + lk;
        const int kg  = ss*16 + kgl;
        const size_t bbase = (size_t)kg*H_N;
        bf16x8 bh0 = Bh[bbase + col0];
        bf16x8 bm0 = Bm[bbase + col0];
        bf16x8 bl0 = Bl[bbase + col0];
        bf16x8 bh1 = Bh[bbase + col1];
        bf16x8 bm1 = Bm[bbase + col1];
        bf16x8 bl1 = Bl[bbase + col1];
        bf16x8 ah[2], am[2], al[2];
        ah[0] = Ahs[kgl*33 + lr];      am[0] = Ams[kgl*33 + lr];      al[0] = Als[kgl*33 + lr];
        ah[1] = Ahs[kgl*33 + 16 + lr]; am[1] = Ams[kgl*33 + 16 + lr]; al[1] = Als[kgl*33 + 16 + lr];
        #pragma unroll
        for (int rt=0;rt<2;++rt){
          hh[rt][0] = MMB(ah[rt], bh0, hh[rt][0]);
          c8[rt][0] = MMB(ah[rt], bm0, c8[rt][0]);
          c8[rt][0] = MMB(am[rt], bh0, c8[rt][0]);
          c8[rt][0] = MMB(ah[rt], bl0, c8[rt][0]);
          c8[rt][0] = MMB(am[rt], bm0, c8[rt][0]);
          c8[rt][0] = MMB(al[rt], bh0, c8[rt][0]);
          hh[rt][1] = MMB(ah[rt], bh1, hh[rt][1]);
          c8[rt][1] = MMB(ah[rt], bm1, c8[rt][1]);
          c8[rt][1] = MMB(am[rt], bh1, c8[rt][1]);
          c8[rt][1] = MMB(ah[rt], bl1, c8[rt][1]);
          c8[rt][1] = MMB(am[rt], bm1, c8[rt][1]);
          c8[rt][1] = MMB(al[rt], bh1, c8[rt][1]);
        }
      }
      #pragma unroll
      for (int rt=0;rt<2;++rt)
        #pragma unroll
        for (int j=0;j<2;++j){
          #pragma unroll
          for (int r=0;r<4;++r) hh64[rt][j][r] += (double)hh[rt][j][r];
          hh[rt][j] = (f32x4){0.f,0.f,0.f,0.f};
        }
    }
    __syncthreads();
  }
#undef MMB
}

// ---------------- inline-split bf16 GEMM (r16/r20 fallback, no ws needed) ----------------
template<bool SWAP, bool CV>
__device__ __forceinline__ void bf16_gemm(
    const float* __restrict__ x, const float* __restrict__ We,
    f32x4 c8[2][2], double hh64[2][2][4],
    int wave, int lr, int lk, int row0)
{
  f32x4 hh[2][2];
  #pragma unroll
  for (int rt=0;rt<2;++rt)
    #pragma unroll
    for (int j=0;j<2;++j){
      hh[rt][j] = (f32x4){0.f,0.f,0.f,0.f};
      c8[rt][j] = (f32x4){0.f,0.f,0.f,0.f};
      #pragma unroll
      for (int r=0;r<4;++r) hh64[rt][j][r] = 0.0;
    }

#define MMB(a,b,c) (SWAP ? __builtin_amdgcn_mfma_f32_16x16x32_bf16((b),(a),(c),0,0,0) \
                         : __builtin_amdgcn_mfma_f32_16x16x32_bf16((a),(b),(c),0,0,0))

  const float* xr0 = x + (size_t)(row0 + lr)*V_N + lk*8;
  const float* xr1 = x + (size_t)(row0 + 16 + lr)*V_N + lk*8;

  for (int s=0; s<32; ++s){
    #pragma unroll
    for (int kin=0;kin<2;++kin){
      float bv0[8], bv1[8];
      const float* bp = We + ((size_t)(s*64 + kin*32 + lk*8))*H_N + wave*32 + lr;
      #pragma unroll
      for (int jj=0;jj<8;++jj){ bv0[jj] = bp[(size_t)jj*H_N]; bv1[jj] = bp[(size_t)jj*H_N + 16]; }
      bf16x8 bh0,bm0,bl0,bh1,bm1,bl1;
      split8<CV>(bv0, bh0, bm0, bl0);
      split8<CV>(bv1, bh1, bm1, bl1);
      bf16x8 ah[2], am[2], al[2];
      float av[8];
      *(float4*)(av)   = *(const float4*)(xr0 + s*64 + kin*32);
      *(float4*)(av+4) = *(const float4*)(xr0 + s*64 + kin*32 + 4);
      split8<CV>(av, ah[0], am[0], al[0]);
      *(float4*)(av)   = *(const float4*)(xr1 + s*64 + kin*32);
      *(float4*)(av+4) = *(const float4*)(xr1 + s*64 + kin*32 + 4);
      split8<CV>(av, ah[1], am[1], al[1]);
      #pragma unroll
      for (int rt=0;rt<2;++rt){
        hh[rt][0] = MMB(ah[rt], bh0, hh[rt][0]);
        c8[rt][0] = MMB(ah[rt], bm0, c8[rt][0]);
        c8[rt][0] = MMB(am[rt], bh0, c8[rt][0]);
        c8[rt][0] = MMB(ah[rt], bl0, c8[rt][0]);
        c8[rt][0] = MMB(am[rt], bm0, c8[rt][0]);
        c8[rt][0] = MMB(al[rt], bh0, c8[rt][0]);
        hh[rt][1] = MMB(ah[rt], bh1, hh[rt][1]);
        c8[rt][1] = MMB(ah[rt], bm1, c8[rt][1]);
        c8[rt][1] = MMB(am[rt], bh1, c8[rt][1]);
        c8[rt][1] = MMB(ah[rt], bl1, c8[rt][1]);
        c8[rt][1] = MMB(am[rt], bm1, c8[rt][1]);
        c8[rt][1] = MMB(al[rt], bh1, c8[rt][1]);
      }
    }
    #pragma unroll
    for (int rt=0;rt<2;++rt)
      #pragma unroll
      for (int j=0;j<2;++j){
        #pragma unroll
        for (int r=0;r<4;++r) hh64[rt][j][r] += (double)hh[rt][j][r];
        hh[rt][j] = (f32x4){0.f,0.f,0.f,0.f};
      }
  }
#undef MMB
}

// ---------------- VALU GEMM fallback ----------------
__device__ __forceinline__ void valu_gemm_and_enc(
    const float* __restrict__ x, const float* __restrict__ We, const float* __restrict__ be,
    float* enc_s, int tid, int row0, unsigned slowtanh)
{
  const int rg = tid >> 6;
  const int c0 = (tid & 63) * 4;
  double acc[4][4];
  #pragma unroll
  for (int r=0;r<4;++r){ acc[r][0]=0.0; acc[r][1]=0.0; acc[r][2]=0.0; acc[r][3]=0.0; }

  for (int v=0; v<V_N; ++v){
    const float* wp = We + (size_t)v*H_N + c0;
    double w0=(double)wp[0], w1=(double)wp[1], w2d=(double)wp[2], w3=(double)wp[3];
    #pragma unroll
    for (int r4=0;r4<4;++r4){
      double xv = (double)x[(size_t)(row0+rg*4+r4)*V_N + v];
      acc[r4][0] = fma(xv, w0, acc[r4][0]);
      acc[r4][1] = fma(xv, w1, acc[r4][1]);
      acc[r4][2] = fma(xv, w2d, acc[r4][2]);
      acc[r4][3] = fma(xv, w3, acc[r4][3]);
    }
  }
  #pragma unroll
  for (int r4=0;r4<4;++r4){
    int r = rg*4 + r4;
    #pragma unroll
    for (int j=0;j<4;++j){
      int c = c0 + j;
      float m1 = (float)(acc[r4][j] + (double)be[c]);
      enc_s[r*257 + c] = (float)tanh_d((double)m1, slowtanh);
    }
  }
}

// ---------------- KE: energies + logits + parallel-RNG fused sampler ----------------
__global__ __launch_bounds__(512) void ke_kernel(
    const float* __restrict__ x, const float* __restrict__ We,
    const float* __restrict__ be, const float* __restrict__ W1,
    const float* __restrict__ b1, const float* __restrict__ w2,
    const float* __restrict__ b2, const float* __restrict__ invt,
    const unsigned* __restrict__ wsu,
    const bf16x8* __restrict__ Bh, const bf16x8* __restrict__ Bm,
    const bf16x8* __restrict__ Bl, int presplit,
    float* __restrict__ energ, float* __restrict__ logit,
    float* __restrict__ probs){
#pragma clang fp contract(off)
  __shared__ float smemf[BROWS*257];        // 32.9 KB; A-split LDS (24.75KB) aliases front
  __shared__ double t2p[BROWS*4*4];
  __shared__ float t2_s[BROWS*4];
  float* enc_s = smemf;
  bf16x8* Ahs = (bf16x8*)smemf;             // 16*33 bf16x8 = 8448 B
  bf16x8* Ams = Ahs + 16*33;
  bf16x8* Als = Ams + 16*33;
  // post-t2 aliases (enc_s dead): sampler staging
  float* en_s = smemf;                      // [0..511]  32 rows x 16 energies
  float* us   = smemf + 512;                // [512..3711]  3200 u values
  unsigned* ps = (unsigned*)(smemf + 3712); // [3712..6911] 3200 props

  const int tid = threadIdx.x;
  const int wave = tid >> 6;
  const int l = tid & 63;
  const int lr = l & 15;
  const int lk = l >> 4;
  const int row0 = blockIdx.x * BROWS;

  const unsigned combo16 = wsu[506];
  const unsigned splmode = wsu[507];
  const unsigned slowtanh = wsu[504];
  const unsigned katflag = wsu[502];
  const float nbeta = __uint_as_float(wsu[505]);

  if (combo16 < 8u && splmode < 2u){
    f32x4 c8[2][2];
    double hh64[2][2][4];
    const bool sw = (combo16 & 1u);
    if (presplit){
      if (splmode == 0u){
        if (sw) bf16_gemm_lds<true ,true >(x, Bh, Bm, Bl, Ahs, Ams, Als, c8, hh64, tid, wave, lr, lk, row0);
        else    bf16_gemm_lds<false,true >(x, Bh, Bm, Bl, Ahs, Ams, Als, c8, hh64, tid, wave, lr, lk, row0);
      } else {
        if (sw) bf16_gemm_lds<true ,false>(x, Bh, Bm, Bl, Ahs, Ams, Als, c8, hh64, tid, wave, lr, lk, row0);
        else    bf16_gemm_lds<false,false>(x, Bh, Bm, Bl, Ahs, Ams, Als, c8, hh64, tid, wave, lr, lk, row0);
      }
    } else if (splmode == 0u){
      if (sw) bf16_gemm<true ,true >(x, We, c8, hh64, wave, lr, lk, row0);
      else    bf16_gemm<false,true >(x, We, c8, hh64, wave, lr, lk, row0);
    } else {
      if (sw) bf16_gemm<true ,false>(x, We, c8, hh64, wave, lr, lk, row0);
      else    bf16_gemm<false,false>(x, We, c8, hh64, wave, lr, lk, row0);
    }
    __syncthreads();
    const int drow = (combo16 >> 1) & 1, dt = (combo16 >> 2) & 1;
    #pragma unroll
    for (int rt=0;rt<2;++rt){
      #pragma unroll
      for (int j=0;j<2;++j){
        #pragma unroll
        for (int r=0;r<4;++r){
          int f = drow ? (lk + 4*r) : (4*lk + r);
          int m = dt ? lr : f;
          int n = dt ? f  : lr;
          int row = rt*16 + m;
          int col = wave*32 + j*16 + n;
          double tot = hh64[rt][j][r] + (double)c8[rt][j][r] + (double)be[col];
          float m1 = (float)tot;                                  // f32 boundary
          enc_s[row*257 + col] = (float)tanh_d((double)m1, slowtanh);
        }
      }
    }
  } else {
    valu_gemm_and_enc(x, We, be, enc_s, tid, row0, slowtanh);
  }
  __syncthreads();

  // t2 = enc @ W1e: 32 rows x 4 q x 4 segs(64) = 512 threads, fixed combine order
  {
    int r = tid >> 4, q = (tid >> 2) & 3, seg = tid & 3;
    double s = 0.0;
    const float* er = enc_s + r*257 + seg*64;
    const float* wq = W1 + seg*64*4 + q;
    #pragma unroll 8
    for (int hh=0; hh<64; ++hh)
      s = fma((double)er[hh], (double)wq[hh*4], s);
    t2p[(r*4+q)*4 + seg] = s;
  }
  __syncthreads();
  if (tid < 128){
    double s = ((t2p[tid*4+0] + t2p[tid*4+1]) + t2p[tid*4+2]) + t2p[tid*4+3];
    t2_s[tid] = (float)s;
  }
  __syncthreads();   // enc_s dead after this -> sampler aliases may write

  // epilogue: energies + logits + en_s stash
  {
    int r = tid >> 4, e = tid & 15;
    float y = 0.0f;
    #pragma unroll
    for (int q=0;q<4;++q){
      float a1f = t2_s[r*4+q] + W1[(H_N+e)*4+q];
      float a2f = a1f + b1[q];
      float hin  = (float)tanh_d((double)a2f, slowtanh);
      float hout = (float)tanh_d((double)hin, slowtanh);
      y = y + hout * w2[q];
    }
    float yb = y + b2[0];
    float en = 3.0f * (float)tanh_d((double)yb, slowtanh);
    size_t gi = (size_t)(row0 + r)*E_N + e;
    energ[gi] = en;
    logit[gi] = nbeta * en;
    en_s[r*16 + e] = en;
  }

  // parallel RNG precompute: 3200 (prop,u) pairs over all 512 threads (values = r23 samp)
  if (katflag == 0u){
    for (int i = tid; i < 3200; i += 512){
      int t = i >> 5;          // 0..99
      int row = i & 31;        // 0..31
      uint32_t b = (uint32_t)(row0 + row);
      uint32_t prop = rbits(wsu[t*5+0], wsu[t*5+1], b) & 15u;
      uint32_t ru   = rbits(wsu[t*5+2], wsu[t*5+3], b);
      us[t*32 + row] = __uint_as_float((ru >> 9) | 0x3f800000u) - 1.0f;
      ps[t*32 + row] = prop;
    }
  }
  __syncthreads();

  // serial Metropolis chains: 32 lanes, light loop (threefry pre-done)
  if (tid < 32){
    const int row = tid;
    float* op = probs + (size_t)(row0 + row)*E_N;
    if (katflag != 0u){
      float c = 0.10f + 0.05f * (float)katflag;
      #pragma unroll
      for (int j0=0; j0<16; j0+=4){
        float4 r4; r4.x=c; r4.y=c; r4.z=c; r4.w=c;
        *(float4*)(op + j0) = r4;
      }
    } else {
      const float* se = en_s + row*16;
      uint32_t cur = rbits(wsu[500], wsu[501], (uint32_t)(row0 + row)) & 15u;
      for (int t=0; t<100; ++t){
        float T = __uint_as_float(wsu[t*5+4]);
        uint32_t prop = ps[t*32 + row];
        float u = us[t*32 + row];
        float ec = se[(int)cur];
        float ep = se[(int)prop];
        float z = (-(ep - ec)) / T;
        z = fminf(z, 0.0f);
        float a = (float)exp((double)z);     // correctly-rounded f32 exp (r23-identical)
        cur = (u < a) ? prop : cur;
      }
      #pragma unroll
      for (int j0=0; j0<16; j0+=4){
        float4 r4;
        r4.x = (cur == (uint32_t)(j0+0)) ? 1.0f : 0.0f;
        r4.y = (cur == (uint32_t)(j0+1)) ? 1.0f : 0.0f;
        r4.z = (cur == (uint32_t)(j0+2)) ? 1.0f : 0.0f;
        r4.w = (cur == (uint32_t)(j0+3)) ? 1.0f : 0.0f;
        *(float4*)(op + j0) = r4;
      }
    }
  }
}

extern "C" void kernel_launch(void* const* d_in, const int* in_sizes, int n_in,
                              void* d_out, int out_size, void* d_ws, size_t ws_size,
                              hipStream_t stream) {
  const float* x   = (const float*)d_in[0];
  const float* We  = (const float*)d_in[1];
  const float* be  = (const float*)d_in[2];
  const float* W1  = (const float*)d_in[3];
  const float* b1  = (const float*)d_in[4];
  const float* w2  = (const float*)d_in[5];
  const float* b2  = (const float*)d_in[6];
  const float* itp = (const float*)d_in[7];
  float* out = (float*)d_out;
  float* probs = out;
  float* energ = out + (size_t)B_N*E_N;
  float* logit = out + 2*(size_t)B_N*E_N;
  unsigned* wsu = (unsigned*)d_ws;

  // workspace: 4KB header | Bh,Bm,Bl (1MB each)
  const size_t bsz = (size_t)KG_N * H_N * 16;
  const size_t need = 4096 + 3*bsz;
  int presplit = (ws_size >= need) ? 1 : 0;
  char* base = (char*)d_ws + 4096;
  bf16x8* Bh = (bf16x8*)(base);
  bf16x8* Bm = (bf16x8*)(base + bsz);
  bf16x8* Bl = (bf16x8*)(base + 2*bsz);

  float log_ratio = (float)log((double)((float)0.1));

  hipLaunchKernelGGL(init_kernel, dim3(65), dim3(1024), 0, stream,
                     wsu, log_ratio, itp, We, Bh, Bm, Bl, presplit);
  hipLaunchKernelGGL(ke_kernel, dim3(B_N/BROWS), dim3(512), 0, stream,
                     x, We, be, W1, b1, w2, b2, itp, wsu,
                     Bh, Bm, Bl, presplit,
                     energ, logit, probs);
}